// Round 1
// baseline (587.272 us; speedup 1.0000x reference)
//
#include <hip/hip_runtime.h>
#include <math.h>

// WaveletDenoiser: 2048 rows x 16384 fp32, 4-level sym8-like DWT, universal
// soft-threshold (exact per-row median of |cd1| via radix select), IDWT.
//
// Level lengths: L=16384 -> T1=8199 -> T2=4107 -> T3=2061 -> T4=1038
// Forward:  ca[t] = sum_k x[s(2t-14+k)] * H[k]
//           cd[t] = sum_k x[s(2t-14+k)] * (-1)^k H[15-k]
//           s(i) = -1-i (i<0), 2L-1-i (i>=L)   [symmetric pad, ext[1:]]
// Inverse:  out[t] = sum_{j=0..7} ca[(t>>1)+j]*cA(j,p) + cdT[(t>>1)+j]*cD(j,p)
//           p = t&1;  p=0: k=2j+1 -> cA=H[14-2j], cD=+H[2j+1]
//                     p=1: k=2j   -> cA=H[15-2j], cD=-H[2j]
//           no boundary clipping needed for t < 2n-14 (proven: m in [0, n-1])

constexpr float HF[16] = {
  0.05441584224308161f,     0.3128715909144659f,     0.6756307362980128f,
  0.5853546836548691f,     -0.015829105256023893f,  -0.2840155429624281f,
  0.00047248457399797254f,  0.128747426620186f,     -0.01736930100202211f,
 -0.04408825393106472f,     0.013981027917015516f,   0.008746094047015655f,
 -0.00487035299301066f,    -0.0003917403729959771f,  0.0006754494059985568f,
 -0.00011747678400228192f
};

__global__ __launch_bounds__(256) void dwt_k(const float* __restrict__ x,
                                             float* __restrict__ ca,
                                             float* __restrict__ cd,
                                             int L, int T) {
  constexpr int B = 256;
  __shared__ float tile[2 * B + 14];
  const int row = blockIdx.y;
  const int t0  = blockIdx.x * B;
  const float* xr = x + (size_t)row * L;
  const int i0 = 2 * t0 - 14;
  for (int i = threadIdx.x; i < 2 * B + 14; i += B) {
    int g = i0 + i;
    if (g < 0) g = -1 - g;
    else if (g >= L) g = 2 * L - 1 - g;
    tile[i] = xr[g];
  }
  __syncthreads();
  const int t = t0 + threadIdx.x;
  if (t < T) {
    float a = 0.f, d = 0.f;
    const int base = 2 * threadIdx.x;
#pragma unroll
    for (int k = 0; k < 16; ++k) {
      const float v = tile[base + k];
      a = fmaf(v, HF[k], a);
      const float g = (k & 1) ? -HF[15 - k] : HF[15 - k];
      d = fmaf(v, g, d);
    }
    ca[(size_t)row * T + t] = a;
    cd[(size_t)row * T + t] = d;
  }
}

__global__ __launch_bounds__(256) void idwt_k(const float* __restrict__ ca,
                                              const float* __restrict__ cd,
                                              const float* __restrict__ thr,
                                              float* __restrict__ out,
                                              int n, int outLen) {
  constexpr int B = 256;
  __shared__ float sa[B / 2 + 8];
  __shared__ float sd[B / 2 + 8];
  const int row = blockIdx.y;
  const int t0  = blockIdx.x * B;
  const int m0  = t0 >> 1;
  const float th = thr[row];
  const float* car = ca + (size_t)row * n;
  const float* cdr = cd + (size_t)row * n;
  for (int i = threadIdx.x; i < B / 2 + 8; i += B) {
    const int m = m0 + i;
    float a = 0.f, d = 0.f;
    if (m < n) { a = car[m]; d = cdr[m]; }
    sa[i] = a;
    const float mag = fabsf(d) - th;           // soft threshold fused here
    sd[i] = (mag > 0.f) ? copysignf(mag, d) : 0.f;
  }
  __syncthreads();
  const int t = t0 + threadIdx.x;
  if (t < outLen) {
    const int b = threadIdx.x >> 1;
    const int p = t & 1;
    float acc = 0.f;
#pragma unroll
    for (int j = 0; j < 8; ++j) {
      const float cA = p ? HF[15 - 2 * j] : HF[14 - 2 * j];
      const float cD = p ? -HF[2 * j]     : HF[2 * j + 1];
      acc = fmaf(sa[b + j], cA, acc);
      acc = fmaf(sd[b + j], cD, acc);
    }
    out[(size_t)row * outLen + t] = acc;
  }
}

// Exact rank-k selection (k = 4099 of 8199) of |cd1| per row via 4-pass 8-bit
// radix select. Non-negative floats are order-isomorphic to their uint bits.
__global__ __launch_bounds__(256) void med_k(const float* __restrict__ cd,
                                             float* __restrict__ thr,
                                             int T, int krank, float scale) {
  __shared__ unsigned sv[8199];
  __shared__ unsigned hist[256];
  __shared__ unsigned scn[256];
  __shared__ unsigned s_prefix, s_k;
  const int row = blockIdx.x;
  const float* p = cd + (size_t)row * T;
  for (int i = threadIdx.x; i < T; i += 256)
    sv[i] = __float_as_uint(fabsf(p[i]));
  if (threadIdx.x == 0) { s_prefix = 0u; s_k = (unsigned)krank; }
  __syncthreads();
  for (int shift = 24; shift >= 0; shift -= 8) {
    hist[threadIdx.x] = 0u;
    __syncthreads();
    const unsigned pref = s_prefix;
    const unsigned k    = s_k;
    for (int i = threadIdx.x; i < T; i += 256) {
      const unsigned v = sv[i];
      if ((unsigned)(((unsigned long long)v) >> (shift + 8)) == pref)
        atomicAdd(&hist[(v >> shift) & 255u], 1u);
    }
    __syncthreads();
    const unsigned h = hist[threadIdx.x];
    scn[threadIdx.x] = h;
    for (int off = 1; off < 256; off <<= 1) {
      __syncthreads();
      const unsigned tv = (threadIdx.x >= (unsigned)off) ? scn[threadIdx.x - off] : 0u;
      __syncthreads();
      scn[threadIdx.x] += tv;
    }
    __syncthreads();
    const unsigned incl = scn[threadIdx.x];
    const unsigned excl = incl - h;
    if (k >= excl && k < incl) {    // exactly one thread (h>0) matches
      s_prefix = (pref << 8) | (unsigned)threadIdx.x;
      s_k = k - excl;
    }
    __syncthreads();
  }
  if (threadIdx.x == 0)
    thr[row] = __uint_as_float(s_prefix) * scale;
}

extern "C" void kernel_launch(void* const* d_in, const int* in_sizes, int n_in,
                              void* d_out, int out_size, void* d_ws, size_t ws_size,
                              hipStream_t stream) {
  const float* x = (const float*)d_in[0];
  float* out = (float*)d_out;
  const int L0 = 16384;
  const int rows = in_sizes[0] / L0;               // 2048
  const int T1 = 8199, T2 = 4107, T3 = 2061, T4 = 1038;

  float* ws = (float*)d_ws;
  size_t off = 0;
  float* A1 = ws + off; off += (size_t)rows * T1;  // ca1, later rec1
  float* D1 = ws + off; off += (size_t)rows * T1;  // cd1 (live until the end)
  float* A2 = ws + off; off += (size_t)rows * T2;  // ca2, later rec2
  float* D2 = ws + off; off += (size_t)rows * T2;
  float* A3 = ws + off; off += (size_t)rows * T3;  // ca3, later rec3
  float* D3 = ws + off; off += (size_t)rows * T3;
  float* A4 = ws + off; off += (size_t)rows * T4;
  float* D4 = ws + off; off += (size_t)rows * T4;
  float* THR = ws + off; off += (size_t)rows;
  // total ~252.4 MB of d_ws

  const dim3 blk(256);
  auto grid = [&](int n) { return dim3((unsigned)((n + 255) / 256), (unsigned)rows); };

  dwt_k<<<grid(T1), blk, 0, stream>>>(x,  A1, D1, L0, T1);
  dwt_k<<<grid(T2), blk, 0, stream>>>(A1, A2, D2, T1, T2);
  dwt_k<<<grid(T3), blk, 0, stream>>>(A2, A3, D3, T2, T3);
  dwt_k<<<grid(T4), blk, 0, stream>>>(A3, A4, D4, T3, T4);

  const float scale = (float)(sqrt(2.0 * log((double)L0)) / 0.6745);
  med_k<<<dim3((unsigned)rows), blk, 0, stream>>>(D1, THR, T1, (T1 - 1) / 2, scale);

  idwt_k<<<grid(T3), blk, 0, stream>>>(A4, D4, THR, A3, T4, T3);   // rec3 (2061)
  idwt_k<<<grid(T2), blk, 0, stream>>>(A3, D3, THR, A2, T3, T2);   // rec2 (4107)
  idwt_k<<<grid(T1), blk, 0, stream>>>(A2, D2, THR, A1, T2, T1);   // rec1 (8199)
  idwt_k<<<grid(L0), blk, 0, stream>>>(A1, D1, THR, out, T1, L0);  // final
}

// Round 2
// 426.282 us; speedup vs baseline: 1.3777x; 1.3777x over previous
//
#include <hip/hip_runtime.h>
#include <math.h>

// WaveletDenoiser: 2048 rows x 16384 fp32, 4-level sym8-like DWT, universal
// soft-threshold (exact per-row median of |cd1| via radix select), IDWT.
//
// Level lengths (logical): L=16384 -> T1=8199 -> T2=4107 -> T3=2061 -> T4=1038
// Padded row strides (mult of 8 floats, 32B-aligned rows):
//   S1=8200, S2=4112, S3=2064, S4=1040
// Forward:  ca[t] = sum_k x[s(2t-14+k)] * H[k]
//           cd[t] = sum_k x[s(2t-14+k)] * (-1)^k H[15-k]
//           s(i) = -1-i (i<0), 2L-1-i (i>=L)   [symmetric pad, ext[1:]]
// Inverse:  out[t] = sum_{j=0..7} ca[(t>>1)+j]*cA(j,p) + cdT[(t>>1)+j]*cD(j,p)
//           p=t&1;  p=0: cA=H[14-2j], cD=+H[2j+1];  p=1: cA=H[15-2j], cD=-H[2j]
//           valid t uses ca indices <= n-1 (no clipping needed; pads unused)
//
// R1 -> R2: removed LDS staging (was LDS-issue bound: 16 scalar ds_read_b32
// per 64-output wave at ~5.8cyc each, only 1.95 TB/s). Now register-direct:
// dwt = 5x dwordx4 loads + 64 FMA per 2-output thread; idwt = 6x dwordx4
// loads + 128 FMA per 8-output thread, all 16B-aligned via padded strides.

constexpr float HF[16] = {
  0.05441584224308161f,     0.3128715909144659f,     0.6756307362980128f,
  0.5853546836548691f,     -0.015829105256023893f,  -0.2840155429624281f,
  0.00047248457399797254f,  0.128747426620186f,     -0.01736930100202211f,
 -0.04408825393106472f,     0.013981027917015516f,   0.008746094047015655f,
 -0.00487035299301066f,    -0.0003917403729959771f,  0.0006754494059985568f,
 -0.00011747678400228192f
};

// Each thread: outputs (ca,cd) at t = 2u, 2u+1 from x[4u-16 .. 4u+3].
__global__ __launch_bounds__(256) void dwt_k(const float* __restrict__ x,
                                             float* __restrict__ ca,
                                             float* __restrict__ cd,
                                             int L, int xStride,
                                             int outStride /* mult of 4 */) {
  const int u = blockIdx.x * 256 + threadIdx.x;
  const int U = outStride >> 1;
  if (u >= U) return;
  const int row = blockIdx.y;
  const float* xr = x + (size_t)row * xStride;

  float w[20];
  const bool interior = (u >= 4) && (4 * u + 3 < L);
  if (interior) {
    const float4* xv = reinterpret_cast<const float4*>(xr + 4 * u - 16);
    const float4 v0 = xv[0], v1 = xv[1], v2 = xv[2], v3 = xv[3], v4 = xv[4];
    w[0]=v0.x;  w[1]=v0.y;  w[2]=v0.z;  w[3]=v0.w;
    w[4]=v1.x;  w[5]=v1.y;  w[6]=v1.z;  w[7]=v1.w;
    w[8]=v2.x;  w[9]=v2.y;  w[10]=v2.z; w[11]=v2.w;
    w[12]=v3.x; w[13]=v3.y; w[14]=v3.z; w[15]=v3.w;
    w[16]=v4.x; w[17]=v4.y; w[18]=v4.z; w[19]=v4.w;
  } else {
#pragma unroll
    for (int k = 0; k < 20; ++k) {
      int g = 4 * u - 16 + k;
      if (g < 0) g = -1 - g;
      else if (g >= L) g = 2 * L - 1 - g;
      w[k] = xr[g];
    }
  }

  float a0 = 0.f, d0 = 0.f, a1 = 0.f, d1 = 0.f;
#pragma unroll
  for (int k = 0; k < 16; ++k) {
    const float g = (k & 1) ? -HF[15 - k] : HF[15 - k];
    a0 = fmaf(w[2 + k], HF[k], a0);
    d0 = fmaf(w[2 + k], g,     d0);
    a1 = fmaf(w[4 + k], HF[k], a1);
    d1 = fmaf(w[4 + k], g,     d1);
  }
  float2* cav = reinterpret_cast<float2*>(ca + (size_t)row * outStride + 2 * u);
  float2* cdv = reinterpret_cast<float2*>(cd + (size_t)row * outStride + 2 * u);
  *cav = make_float2(a0, a1);
  *cdv = make_float2(d0, d1);
}

// Each thread: 8 outputs t = 8u..8u+7 from ca/cd[4u .. 4u+11] (pads make all
// vector accesses in-row; valid outputs never consume pad coefficients).
__global__ __launch_bounds__(256) void idwt_k(const float* __restrict__ ca,
                                              const float* __restrict__ cd,
                                              const float* __restrict__ thr,
                                              float* __restrict__ out,
                                              int inStride,
                                              int outStride /* mult of 8 */) {
  const int u = blockIdx.x * 256 + threadIdx.x;
  const int U = outStride >> 3;
  if (u >= U) return;
  const int row = blockIdx.y;
  const float th = thr[row];
  const float* car = ca + (size_t)row * inStride + 4 * u;
  const float* cdr = cd + (size_t)row * inStride + 4 * u;

  const float4* av = reinterpret_cast<const float4*>(car);
  const float4* dv = reinterpret_cast<const float4*>(cdr);
  const float4 a0 = av[0], a1 = av[1], a2 = av[2];
  const float4 e0 = dv[0], e1 = dv[1], e2 = dv[2];
  const float A[12] = {a0.x,a0.y,a0.z,a0.w, a1.x,a1.y,a1.z,a1.w, a2.x,a2.y,a2.z,a2.w};
  const float Dr[12] = {e0.x,e0.y,e0.z,e0.w, e1.x,e1.y,e1.z,e1.w, e2.x,e2.y,e2.z,e2.w};
  float Ds[12];
#pragma unroll
  for (int j = 0; j < 12; ++j) {
    const float d = Dr[j];
    const float mag = fabsf(d) - th;
    Ds[j] = (mag > 0.f) ? copysignf(mag, d) : 0.f;
  }

  float o[8];
#pragma unroll
  for (int e = 0; e < 8; ++e) {
    const int b = e >> 1;
    float acc = 0.f;
#pragma unroll
    for (int j = 0; j < 8; ++j) {
      const float cA = (e & 1) ? HF[15 - 2 * j] : HF[14 - 2 * j];
      const float cD = (e & 1) ? -HF[2 * j]     : HF[2 * j + 1];
      acc = fmaf(A[b + j], cA, acc);
      acc = fmaf(Ds[b + j], cD, acc);
    }
    o[e] = acc;
  }
  float4* ov = reinterpret_cast<float4*>(out + (size_t)row * outStride + 8 * u);
  ov[0] = make_float4(o[0], o[1], o[2], o[3]);
  ov[1] = make_float4(o[4], o[5], o[6], o[7]);
}

// Exact rank-k selection (k = 4099 of 8199) of |cd1| per row via 4-pass 8-bit
// radix select. Non-negative floats are order-isomorphic to their uint bits.
__global__ __launch_bounds__(256) void med_k(const float* __restrict__ cd,
                                             float* __restrict__ thr,
                                             int T, int stride, int krank,
                                             float scale) {
  __shared__ unsigned sv[8199];
  __shared__ unsigned hist[256];
  __shared__ unsigned scn[256];
  __shared__ unsigned s_prefix, s_k;
  const int row = blockIdx.x;
  const float* p = cd + (size_t)row * stride;
  for (int i = threadIdx.x; i < T; i += 256)
    sv[i] = __float_as_uint(fabsf(p[i]));
  if (threadIdx.x == 0) { s_prefix = 0u; s_k = (unsigned)krank; }
  __syncthreads();
  for (int shift = 24; shift >= 0; shift -= 8) {
    hist[threadIdx.x] = 0u;
    __syncthreads();
    const unsigned pref = s_prefix;
    const unsigned k    = s_k;
    for (int i = threadIdx.x; i < T; i += 256) {
      const unsigned v = sv[i];
      if ((unsigned)(((unsigned long long)v) >> (shift + 8)) == pref)
        atomicAdd(&hist[(v >> shift) & 255u], 1u);
    }
    __syncthreads();
    const unsigned h = hist[threadIdx.x];
    scn[threadIdx.x] = h;
    for (int off = 1; off < 256; off <<= 1) {
      __syncthreads();
      const unsigned tv = (threadIdx.x >= (unsigned)off) ? scn[threadIdx.x - off] : 0u;
      __syncthreads();
      scn[threadIdx.x] += tv;
    }
    __syncthreads();
    const unsigned incl = scn[threadIdx.x];
    const unsigned excl = incl - h;
    if (k >= excl && k < incl) {    // exactly one thread (h>0) matches
      s_prefix = (pref << 8) | (unsigned)threadIdx.x;
      s_k = k - excl;
    }
    __syncthreads();
  }
  if (threadIdx.x == 0)
    thr[row] = __uint_as_float(s_prefix) * scale;
}

extern "C" void kernel_launch(void* const* d_in, const int* in_sizes, int n_in,
                              void* d_out, int out_size, void* d_ws, size_t ws_size,
                              hipStream_t stream) {
  const float* x = (const float*)d_in[0];
  float* out = (float*)d_out;
  const int L0 = 16384;
  const int rows = in_sizes[0] / L0;               // 2048
  const int T1 = 8199, T2 = 4107, T3 = 2061;
  const int S1 = 8200, S2 = 4112, S3 = 2064, S4 = 1040;  // padded strides

  float* ws = (float*)d_ws;
  size_t off = 0;
  float* A1 = ws + off; off += (size_t)rows * S1;  // ca1, later rec1
  float* D1 = ws + off; off += (size_t)rows * S1;  // cd1 (live until the end)
  float* A2 = ws + off; off += (size_t)rows * S2;  // ca2, later rec2
  float* D2 = ws + off; off += (size_t)rows * S2;
  float* A3 = ws + off; off += (size_t)rows * S3;  // ca3, later rec3
  float* D3 = ws + off; off += (size_t)rows * S3;
  float* A4 = ws + off; off += (size_t)rows * S4;
  float* D4 = ws + off; off += (size_t)rows * S4;
  float* THR = ws + off; off += (size_t)rows;
  // total ~253 MB of d_ws

  const dim3 blk(256);
  auto dgrid = [&](int S) { return dim3((unsigned)((S / 2 + 255) / 256), (unsigned)rows); };
  auto igrid = [&](int S) { return dim3((unsigned)((S / 8 + 255) / 256), (unsigned)rows); };

  dwt_k<<<dgrid(S1), blk, 0, stream>>>(x,  A1, D1, L0, L0, S1);
  dwt_k<<<dgrid(S2), blk, 0, stream>>>(A1, A2, D2, T1, S1, S2);
  dwt_k<<<dgrid(S3), blk, 0, stream>>>(A2, A3, D3, T2, S2, S3);
  dwt_k<<<dgrid(S4), blk, 0, stream>>>(A3, A4, D4, T3, S3, S4);

  const float scale = (float)(sqrt(2.0 * log((double)L0)) / 0.6745);
  med_k<<<dim3((unsigned)rows), blk, 0, stream>>>(D1, THR, T1, S1, (T1 - 1) / 2, scale);

  idwt_k<<<igrid(S3), blk, 0, stream>>>(A4, D4, THR, A3, S4, S3);   // rec3
  idwt_k<<<igrid(S2), blk, 0, stream>>>(A3, D3, THR, A2, S3, S2);   // rec2
  idwt_k<<<igrid(S1), blk, 0, stream>>>(A2, D2, THR, A1, S2, S1);   // rec1
  idwt_k<<<igrid(L0), blk, 0, stream>>>(A1, D1, THR, out, S1, L0);  // final
}